// Round 18
// baseline (2286.541 us; speedup 1.0000x reference)
//
#include <hip/hip_runtime.h>

#define TT 2048
#define HH 64
#define II 6
#define OO 6
#define NTHR 320   // 5 waves: XA(0) W0(1) WX(2) W1(3) WF(4); XA+WF share SIMD0

typedef float    f32x4 __attribute__((ext_vector_type(4)));
typedef float    f32x2 __attribute__((ext_vector_type(2)));
typedef _Float16 f16x8 __attribute__((ext_vector_type(8)));

__device__ __forceinline__ float fast_sig(float v) {
    return __builtin_amdgcn_rcpf(1.0f + __expf(-v));
}
__device__ __forceinline__ float fast_tanh(float v) {
    return 1.0f - 2.0f * __builtin_amdgcn_rcpf(__expf(2.0f * v) + 1.0f);
}

#define MFMA(a, b, c) __builtin_amdgcn_mfma_f32_16x16x32_f16((a), (b), (c), 0, 0, 0)

// LDS-only barrier: global loads/stores stay in flight across it.
#define LGKM_BARRIER() asm volatile("s_waitcnt lgkmcnt(0)\ns_barrier" ::: "memory")

__global__
__attribute__((amdgpu_flat_work_group_size(NTHR, NTHR)))
__attribute__((amdgpu_waves_per_eu(2)))   // cap VGPR at 256: no spill, 2-wave SIMD0 fits
void lstm_mfma_kernel(const float* __restrict__ x,
                      const float* __restrict__ Wih0, const float* __restrict__ Whh0,
                      const float* __restrict__ b0,
                      const float* __restrict__ Wih1, const float* __restrict__ Whh1,
                      const float* __restrict__ b1,
                      const float* __restrict__ W1, const float* __restrict__ bf1,
                      const float* __restrict__ W2, const float* __restrict__ bf2,
                      float* __restrict__ out)
{
    const int row  = blockIdx.x;      // one batch row per block
    const int tid  = threadIdx.x;
    const int wid  = tid >> 6;        // 0=XA 1=W0 2=WX 3=W1 4=WF
    const int lane = tid & 63;
    const int n    = lane & 15;       // MFMA col-lane (B-col / D-col)
    const int q    = lane >> 4;       // k-group: elems k = 8q..8q+7 (+32 for hi chunk)

    __shared__ __attribute__((aligned(16))) _Float16 H0[2][HH];
    __shared__ __attribute__((aligned(16))) _Float16 H1[2][HH];
    __shared__ __attribute__((aligned(16))) _Float16 Rb[HH];
    __shared__ __attribute__((aligned(16))) float    XG0[2][4 * HH];  // xg0 strip f32
    __shared__ __attribute__((aligned(16))) float    XG1[2][4 * HH];  // xg1 strip f32

    // all init + prologue done by wave 0, published by the single __syncthreads
    if (tid < HH) {
        H0[0][tid] = (_Float16)0.f; H0[1][tid] = (_Float16)0.f;
        H1[0][tid] = (_Float16)0.f; H1[1][tid] = (_Float16)0.f;
        Rb[tid]    = (_Float16)0.f;
    }

    // elem i <-> k = kbase + 8q + i (same map as A-frag reads, so it cancels)
    auto mk = [&](const float* W, int r, int ld, int kbase, int kmax, bool rok) {
        f16x8 f;
        #pragma unroll
        for (int i = 0; i < 8; ++i) {
            int kk = kbase + 8 * q + i;
            f[i] = (rok && kk < kmax) ? (_Float16)W[r * ld + kk] : (_Float16)0.f;
        }
        return f;
    };
    const f32x4 zero4 = {0.f, 0.f, 0.f, 0.f};

    f16x8 fragG[32], fragY[2];
    float bv[16];
    float bf2v = 0.f;
    #pragma unroll
    for (int m = 0; m < 16; ++m) bv[m] = 0.f;
    fragY[0] = mk(W1, 0, HH, 0, HH, false);   // zero
    fragY[1] = fragY[0];
    #pragma unroll
    for (int m = 0; m < 32; ++m) fragG[m] = fragY[0];

    if (wid == 0) {            // XA: Wih0 (k<6 only, 1 chunk) rows 16m+n
        #pragma unroll
        for (int m = 0; m < 16; ++m) {
            fragG[m] = mk(Wih0, 16 * m + n, II, 0, II, true);
            bv[m] = b0[16 * m + n];
        }
    } else if (wid == 1) {     // W0: Whh0 rows 16m+n, 2 k-chunks
        #pragma unroll
        for (int m = 0; m < 16; ++m) {
            fragG[2 * m + 0] = mk(Whh0, 16 * m + n, HH, 0,  HH, true);
            fragG[2 * m + 1] = mk(Whh0, 16 * m + n, HH, 32, HH, true);
        }
    } else if (wid == 2) {     // WX: Wih1 rows
        #pragma unroll
        for (int m = 0; m < 16; ++m) {
            fragG[2 * m + 0] = mk(Wih1, 16 * m + n, HH, 0,  HH, true);
            fragG[2 * m + 1] = mk(Wih1, 16 * m + n, HH, 32, HH, true);
            bv[m] = b1[16 * m + n];
        }
    } else if (wid == 3) {     // W1: Whh1 rows
        #pragma unroll
        for (int m = 0; m < 16; ++m) {
            fragG[2 * m + 0] = mk(Whh1, 16 * m + n, HH, 0,  HH, true);
            fragG[2 * m + 1] = mk(Whh1, 16 * m + n, HH, 32, HH, true);
        }
    } else {                   // WF: FC1 rows 16m+n (m<4) + FC2 row n
        #pragma unroll
        for (int m = 0; m < 4; ++m) {
            fragG[2 * m + 0] = mk(W1, 16 * m + n, HH, 0,  HH, true);
            fragG[2 * m + 1] = mk(W1, 16 * m + n, HH, 32, HH, true);
            bv[m] = bf1[16 * m + n];
        }
        fragY[0] = mk(W2, n, HH, 0,  HH, n < OO);
        fragY[1] = mk(W2, n, HH, 32, HH, n < OO);
        bf2v = (n < OO) ? bf2[n] : 0.f;
    }

    // x register pipeline (XA only); opaque VGPR ptr -> lazy vector loads
    const float* xrow = x + (size_t)row * TT * II;
    {
        unsigned long long p = (unsigned long long)xrow;
        asm volatile("" : "+v"(p));
        xrow = (const float*)p;
    }
    float xc[6] = {0.f, 0.f, 0.f, 0.f, 0.f, 0.f};

    if (wid == 0) {            // prologue: xg0[0] -> XG0 slot 0; xc = x[1]
        float x0[6];
        #pragma unroll
        for (int k2 = 0; k2 < 6; ++k2) x0[k2] = xrow[k2];
        f16x8 a2;
        #pragma unroll
        for (int i = 0; i < 6; ++i) a2[i] = (_Float16)x0[i];
        a2[6] = (_Float16)0.f; a2[7] = (_Float16)0.f;
        #pragma unroll
        for (int m = 0; m < 16; ++m) {
            f32x4 acc = MFMA(a2, fragG[m], zero4);
            if (lane < 16) XG0[0][16 * m + n] = acc[0] + bv[m];
        }
        #pragma unroll
        for (int k2 = 0; k2 < 6; ++k2) xc[k2] = xrow[II + k2];
    }

    float* outrow = out + (size_t)row * TT * OO;
    float cst[4] = {0.f, 0.f, 0.f, 0.f};   // W0/W1: cell state, 4 units/lane
    f16x8 rf0 = fragY[0], rf1 = fragY[0];  // WF: reg-carried r-frags (start zero-ish)
    if (wid == 4) { rf0 = mk(W1, 0, HH, 0, HH, false); rf1 = rf0; }

    __syncthreads();   // publish init + prologue

    // Slot algebra (all cross-wave handoffs are 1 epoch apart):
    //  XG0: XA@t writes xg0[t+1] -> slot (t+1)&1 ; W0@t reads xg0[t] -> slot t&1
    //  H0 : W0@t writes h0[t]    -> slot t&1     ; W0/WX@t read h0[t-1] -> (t+1)&1
    //  XG1: WX@t writes xg1[t-1] -> slot (t+1)&1 ; W1@t reads xg1[t-2] -> slot t&1
    //  H1 : W1@t writes h1[t-2]  -> slot t&1     ; W1/WF@t read h1[t-3] -> (t+1)&1
    //  Rb : WF-private (same-wave write->read, lgkmcnt-ordered)
    for (int t = 0; t <= TT + 3; ++t) {
        const int sp = (t + 1) & 1;
        const int sc = t & 1;

        if (wid == 0) {            // ---- XA: xg0[t+1]
            const int tn = (t + 2 < TT) ? t + 2 : TT - 1;
            f32x4 xn03 = *reinterpret_cast<const f32x4*>(xrow + (size_t)tn * II);
            f32x2 xn45 = *reinterpret_cast<const f32x2*>(xrow + (size_t)tn * II + 4);
            f16x8 a2;
            #pragma unroll
            for (int i = 0; i < 6; ++i) a2[i] = (_Float16)xc[i];
            a2[6] = (_Float16)0.f; a2[7] = (_Float16)0.f;
            #pragma unroll
            for (int m = 0; m < 16; ++m) {
                f32x4 acc = MFMA(a2, fragG[m], zero4);
                if (t + 1 < TT && lane < 16) XG0[sp][16 * m + n] = acc[0] + bv[m];
            }
            xc[0] = xn03[0]; xc[1] = xn03[1]; xc[2] = xn03[2];
            xc[3] = xn03[3]; xc[4] = xn45[0]; xc[5] = xn45[1];
        } else if (wid == 1) {     // ---- W0: layer0 @ t (in-wave recurrence)
            const f16x8 a0 = *reinterpret_cast<const f16x8*>(&H0[sp][8 * q]);
            const f16x8 a1 = *reinterpret_cast<const f16x8*>(&H0[sp][32 + 8 * q]);
            float gv[16];
            #pragma unroll
            for (int m = 0; m < 16; ++m) {
                float xgv = XG0[sc][16 * m + n];
                f32x4 acc0 = MFMA(a0, fragG[2 * m + 0], zero4);
                f32x4 acc1 = MFMA(a1, fragG[2 * m + 1], zero4);
                gv[m] = (acc0[0] + acc1[0]) + xgv;
            }
            if (t < TT) {
                #pragma unroll
                for (int j = 0; j < 4; ++j) {   // unit u = 16j+n
                    float i_ = fast_sig(gv[j]),      f_ = fast_sig(gv[4 + j]);
                    float g_ = fast_tanh(gv[8 + j]), o_ = fast_sig(gv[12 + j]);
                    cst[j] = f_ * cst[j] + i_ * g_;
                    float h = o_ * fast_tanh(cst[j]);
                    if (lane < 16) H0[sc][16 * j + n] = (_Float16)h;
                }
            }
        } else if (wid == 2) {     // ---- WX: xg1[t-1]
            const f16x8 a0 = *reinterpret_cast<const f16x8*>(&H0[sp][8 * q]);
            const f16x8 a1 = *reinterpret_cast<const f16x8*>(&H0[sp][32 + 8 * q]);
            #pragma unroll
            for (int m = 0; m < 16; ++m) {
                f32x4 acc0 = MFMA(a0, fragG[2 * m + 0], zero4);
                f32x4 acc1 = MFMA(a1, fragG[2 * m + 1], zero4);
                if (t >= 1 && t <= TT && lane < 16)
                    XG1[sp][16 * m + n] = (acc0[0] + acc1[0]) + bv[m];
            }
        } else if (wid == 3) {     // ---- W1: layer1 @ s2 = t-2 (in-wave recurrence)
            const int s2 = t - 2;
            const f16x8 a0 = *reinterpret_cast<const f16x8*>(&H1[sp][8 * q]);
            const f16x8 a1 = *reinterpret_cast<const f16x8*>(&H1[sp][32 + 8 * q]);
            float gv[16];
            #pragma unroll
            for (int m = 0; m < 16; ++m) {
                float xgv = XG1[sc][16 * m + n];
                f32x4 acc0 = MFMA(a0, fragG[2 * m + 0], zero4);
                f32x4 acc1 = MFMA(a1, fragG[2 * m + 1], zero4);
                gv[m] = (acc0[0] + acc1[0]) + xgv;
            }
            if (s2 >= 0 && s2 < TT) {
                #pragma unroll
                for (int j = 0; j < 4; ++j) {
                    float i_ = fast_sig(gv[j]),      f_ = fast_sig(gv[4 + j]);
                    float g_ = fast_tanh(gv[8 + j]), o_ = fast_sig(gv[12 + j]);
                    cst[j] = f_ * cst[j] + i_ * g_;
                    float h = o_ * fast_tanh(cst[j]);
                    if (lane < 16) H1[sc][16 * j + n] = (_Float16)h;
                }
            }
        } else {                   // ---- WF: FC2 @ s4 (reg frags), FC1 @ s3 -> Rb
            const int s3 = t - 3, s4 = t - 4;
            f32x4 o0 = MFMA(rf0, fragY[0], zero4);
            f32x4 o1 = MFMA(rf1, fragY[1], zero4);
            if (s4 >= 0 && s4 < TT && lane < OO)
                outrow[(size_t)s4 * OO + lane] = (o0[0] + o1[0]) + bf2v;
            const f16x8 a0 = *reinterpret_cast<const f16x8*>(&H1[sp][8 * q]);
            const f16x8 a1 = *reinterpret_cast<const f16x8*>(&H1[sp][32 + 8 * q]);
            #pragma unroll
            for (int m = 0; m < 4; ++m) {
                f32x4 f0 = MFMA(a0, fragG[2 * m + 0], zero4);
                f32x4 f1 = MFMA(a1, fragG[2 * m + 1], zero4);
                float r = fmaxf((f0[0] + f1[0]) + bv[m], 0.f);
                if (lane < 16) Rb[16 * m + n] = (_Float16)r;   // garbage ok: s4-guarded
            }
            // same-wave readback for next epoch's FC2 (lgkmcnt orders write->read)
            rf0 = *reinterpret_cast<const f16x8*>(&Rb[8 * q]);
            rf1 = *reinterpret_cast<const f16x8*>(&Rb[32 + 8 * q]);
        }
        LGKM_BARRIER();   // one barrier per step; global ops stay in flight
    }
}

extern "C" void kernel_launch(void* const* d_in, const int* in_sizes, int n_in,
                              void* d_out, int out_size, void* d_ws, size_t ws_size,
                              hipStream_t stream) {
    const float* xp   = (const float*)d_in[0];
    const float* Wih0 = (const float*)d_in[1];
    const float* Whh0 = (const float*)d_in[2];
    const float* b0   = (const float*)d_in[3];
    const float* Wih1 = (const float*)d_in[4];
    const float* Whh1 = (const float*)d_in[5];
    const float* b1   = (const float*)d_in[6];
    const float* W1   = (const float*)d_in[7];
    const float* bf1  = (const float*)d_in[8];
    const float* W2   = (const float*)d_in[9];
    const float* bf2  = (const float*)d_in[10];
    float* outp = (float*)d_out;

    lstm_mfma_kernel<<<dim3(256), dim3(NTHR), 0, stream>>>(
        xp, Wih0, Whh0, b0, Wih1, Whh1, b1, W1, bf1, W2, bf2, outp);
}

// Round 19
// 2213.652 us; speedup vs baseline: 1.0329x; 1.0329x over previous
//
#include <hip/hip_runtime.h>

#define TT 2048
#define HH 64
#define II 6
#define OO 6
#define MB 16      // batch rows per block -> 16 blocks
#define NTHR 512   // 8 waves: 4 A (layer0+FC1), 4 B (layer1; w0 FC2, w3 x-stage)

typedef float    f32x4 __attribute__((ext_vector_type(4)));
typedef float    f32x2 __attribute__((ext_vector_type(2)));
typedef _Float16 f16x8 __attribute__((ext_vector_type(8)));
typedef _Float16 f16x4 __attribute__((ext_vector_type(4)));
typedef _Float16 f16x2 __attribute__((ext_vector_type(2)));

__device__ __forceinline__ float fast_sig(float v) {
    return __builtin_amdgcn_rcpf(1.0f + __expf(-v));
}
__device__ __forceinline__ float fast_tanh(float v) {
    return 1.0f - 2.0f * __builtin_amdgcn_rcpf(__expf(2.0f * v) + 1.0f);
}

#define MFMA(a, b, c) __builtin_amdgcn_mfma_f32_16x16x32_f16((a), (b), (c), 0, 0, 0)
#define LGKM_BARRIER() asm volatile("s_waitcnt lgkmcnt(0)\ns_barrier" ::: "memory")

__global__
__attribute__((amdgpu_flat_work_group_size(NTHR, NTHR)))
__attribute__((amdgpu_waves_per_eu(2, 2)))
void lstm_mfma_kernel(const float* __restrict__ x,
                      const float* __restrict__ Wih0, const float* __restrict__ Whh0,
                      const float* __restrict__ b0,
                      const float* __restrict__ Wih1, const float* __restrict__ Whh1,
                      const float* __restrict__ b1,
                      const float* __restrict__ W1, const float* __restrict__ bf1,
                      const float* __restrict__ W2, const float* __restrict__ bf2,
                      float* __restrict__ out)
{
    const int row0 = blockIdx.x * MB;   // 16 batch rows per block
    const int tid  = threadIdx.x;
    const int wid  = tid >> 6;          // 0-3: A-role, 4-7: B-role
    const int lane = tid & 63;
    const int n    = lane & 15;         // B-col lane = BATCH ; A-row lane = unit 16w+n
    const int q    = lane >> 4;         // k-group; D rows (units) 4q+r
    const bool isA = wid < 4;
    const int  w   = wid & 3;

    // frag-ready h storage: [slot][kchunk*128 + batch*8 + (k&7)], f16
    __shared__ __attribute__((aligned(16))) _Float16 H0[4][1024];
    __shared__ __attribute__((aligned(16))) _Float16 H1[2][1024];
    __shared__ __attribute__((aligned(16))) _Float16 Rb[2][1024];
    __shared__ __attribute__((aligned(16))) _Float16 XT[2][128];  // x tile, chunk0

    {
        _Float16* p = &H0[0][0];
        for (int i = tid; i < 4 * 1024; i += NTHR) p[i] = (_Float16)0.f;
        p = &H1[0][0];
        for (int i = tid; i < 2 * 1024; i += NTHR) p[i] = (_Float16)0.f;
        p = &Rb[0][0];
        for (int i = tid; i < 2 * 1024; i += NTHR) p[i] = (_Float16)0.f;
        p = &XT[0][0];
        for (int i = tid; i < 2 * 128; i += NTHR) p[i] = (_Float16)0.f;
    }

    // weight A-frag: row = lane&15 (= unit within tile), elem i <-> k = kbase+8q+i
    auto mk = [&](const float* W, int r, int ld, int kbase, int kmax, bool rok) {
        f16x8 f;
        #pragma unroll
        for (int i = 0; i < 8; ++i) {
            int kk = kbase + 8 * q + i;
            f[i] = (rok && kk < kmax) ? (_Float16)W[r * ld + kk] : (_Float16)0.f;
        }
        return f;
    };
    const f32x4 zero4 = {0.f, 0.f, 0.f, 0.f};
    f16x8 zero8;
    #pragma unroll
    for (int i = 0; i < 8; ++i) zero8[i] = (_Float16)0.f;

    f16x8 FR[18];
    #pragma unroll
    for (int i = 0; i < 18; ++i) FR[i] = zero8;
    f32x4 biasv[4] = {zero4, zero4, zero4, zero4};
    f32x4 biasF = zero4;

    if (isA) {
        #pragma unroll
        for (int g = 0; g < 4; ++g) {           // layer0: Whh0 2 chunks + Wih0 1
            const int r0 = g * HH + 16 * w + n;         // A-frag row (unit 16w+n)
            FR[2 * g + 0] = mk(Whh0, r0, HH, 0,  HH, true);
            FR[2 * g + 1] = mk(Whh0, r0, HH, 32, HH, true);
            FR[8 + g]     = mk(Wih0, r0, II, 0,  II, true);
            const int u = g * HH + 16 * w + 4 * q;      // D rows: units 4q+r
            biasv[g] = f32x4{b0[u], b0[u + 1], b0[u + 2], b0[u + 3]};
        }
        FR[12] = mk(W1, 16 * w + n, HH, 0,  HH, true);  // FC1
        FR[13] = mk(W1, 16 * w + n, HH, 32, HH, true);
        const int uf = 16 * w + 4 * q;
        biasF = f32x4{bf1[uf], bf1[uf + 1], bf1[uf + 2], bf1[uf + 3]};
    } else {
        #pragma unroll
        for (int g = 0; g < 4; ++g) {           // layer1 fused: Wih1 + Whh1
            const int r0 = g * HH + 16 * w + n;
            FR[4 * g + 0] = mk(Wih1, r0, HH, 0,  HH, true);   // @ h0[t-2]
            FR[4 * g + 1] = mk(Wih1, r0, HH, 32, HH, true);
            FR[4 * g + 2] = mk(Whh1, r0, HH, 0,  HH, true);   // @ h1[t-3]
            FR[4 * g + 3] = mk(Whh1, r0, HH, 32, HH, true);
            const int u = g * HH + 16 * w + 4 * q;
            biasv[g] = f32x4{b1[u], b1[u + 1], b1[u + 2], b1[u + 3]};
        }
        if (w == 0) {                           // FC2
            FR[16] = mk(W2, n, HH, 0,  HH, n < OO);
            FR[17] = mk(W2, n, HH, 32, HH, n < OO);
            #pragma unroll
            for (int r2 = 0; r2 < 4; ++r2) {
                const int u = 4 * q + r2;
                biasF[r2] = (u < OO) ? bf2[u] : 0.f;
            }
        }
    }

    // x stager: wave 7, lanes 0-15 own one batch row each
    const float* xpl = nullptr;
    if (wid == 7 && lane < MB) {
        const float* p = x + (size_t)(row0 + lane) * TT * II;
        unsigned long long pp = (unsigned long long)p;
        asm volatile("" : "+v"(pp));            // force VGPR (vmcnt) loads
        xpl = (const float*)pp;
        f32x2 u0 = *(const f32x2*)(xpl + 0);    // prologue: x[0] -> XT[0]
        f32x2 u1 = *(const f32x2*)(xpl + 2);
        f32x2 u2 = *(const f32x2*)(xpl + 4);
        *(f16x4*)&XT[0][lane * 8] =
            f16x4{(_Float16)u0[0], (_Float16)u0[1], (_Float16)u1[0], (_Float16)u1[1]};
        *(f16x2*)&XT[0][lane * 8 + 4] = f16x2{(_Float16)u2[0], (_Float16)u2[1]};
    }

    float* outbase = out + (size_t)row0 * TT * OO;
    f32x4 cst = zero4;   // 4 units' cell state (batch n) per lane

    __syncthreads();

    // Slot algebra (verified R13): writes at step e visible at e+1.
    //  H0: A writes t -> t&3; A reads t-1 -> (t+3)&3; B reads t-2 -> (t+2)&3
    //  H1: B writes t-2 -> t&1; A(FC1)/B read t-3 -> (t+1)&1
    //  Rb: A writes t-3 -> (t+1)&1; B-w0 reads t-4 -> t&1
    //  XT: w7 writes x[t+1] -> (t+1)&1; A reads x[t] -> t&1
    for (int t = 0; t <= TT + 3; ++t) {
        const int s0r = (t + 3) & 3, s0w = t & 3, s0b = (t + 2) & 3;
        const int sp = (t + 1) & 1, sc = t & 1;

        if (isA) {
            const f16x8 ha0 = *(const f16x8*)&H0[s0r][q * 128 + n * 8];
            const f16x8 ha1 = *(const f16x8*)&H0[s0r][(4 + q) * 128 + n * 8];
            f16x8 xb = zero8;
            if (q == 0) xb = *(const f16x8*)&XT[sc][n * 8];   // chunk0 only (k<6)
            const f16x8 hb0 = *(const f16x8*)&H1[sp][q * 128 + n * 8];
            const f16x8 hb1 = *(const f16x8*)&H1[sp][(4 + q) * 128 + n * 8];

            f32x4 d0, d1, d2, d3;
            {   // 12 independent gate MFMAs (A=weights, B=h/x tile)
                f32x4 p0 = MFMA(FR[0], ha0, biasv[0]);
                f32x4 p1 = MFMA(FR[1], ha1, zero4);
                f32x4 p2 = MFMA(FR[8], xb, zero4);
                d0 = (p0 + p1) + p2;
                p0 = MFMA(FR[2], ha0, biasv[1]);
                p1 = MFMA(FR[3], ha1, zero4);
                p2 = MFMA(FR[9], xb, zero4);
                d1 = (p0 + p1) + p2;
                p0 = MFMA(FR[4], ha0, biasv[2]);
                p1 = MFMA(FR[5], ha1, zero4);
                p2 = MFMA(FR[10], xb, zero4);
                d2 = (p0 + p1) + p2;
                p0 = MFMA(FR[6], ha0, biasv[3]);
                p1 = MFMA(FR[7], ha1, zero4);
                p2 = MFMA(FR[11], xb, zero4);
                d3 = (p0 + p1) + p2;
            }
            f32x4 f0 = MFMA(FR[12], hb0, biasF);   // FC1 @ s3=t-3
            f32x4 f1 = MFMA(FR[13], hb1, zero4);
            f32x4 fr = f0 + f1;

            if (t >= 3 && t < TT + 3) {            // 0 <= s3 < TT
                f16x4 rv = {(_Float16)fmaxf(fr[0], 0.f), (_Float16)fmaxf(fr[1], 0.f),
                            (_Float16)fmaxf(fr[2], 0.f), (_Float16)fmaxf(fr[3], 0.f)};
                *(f16x4*)&Rb[sp][(2 * w + (q >> 1)) * 128 + n * 8 + (q & 1) * 4] = rv;
            }
            if (t < TT) {
                float hv[4];
                #pragma unroll
                for (int r2 = 0; r2 < 4; ++r2) {
                    float i_ = fast_sig(d0[r2]), f_ = fast_sig(d1[r2]);
                    float g_ = fast_tanh(d2[r2]), o_ = fast_sig(d3[r2]);
                    cst[r2] = f_ * cst[r2] + i_ * g_;
                    hv[r2] = o_ * fast_tanh(cst[r2]);
                }
                f16x4 hh = {(_Float16)hv[0], (_Float16)hv[1],
                            (_Float16)hv[2], (_Float16)hv[3]};
                *(f16x4*)&H0[s0w][(2 * w + (q >> 1)) * 128 + n * 8 + (q & 1) * 4] = hh;
            }
        } else {
            // x prefetch first (w7): full step of latency cover before cvt/write
            f32x2 u0, u1, u2;
            if (wid == 7 && lane < MB) {
                const int tn = (t + 1 < TT) ? t + 1 : TT - 1;
                const float* xp2 = xpl + (size_t)tn * II;
                u0 = *(const f32x2*)(xp2 + 0);
                u1 = *(const f32x2*)(xp2 + 2);
                u2 = *(const f32x2*)(xp2 + 4);
            }
            const f16x8 h00 = *(const f16x8*)&H0[s0b][q * 128 + n * 8];
            const f16x8 h01 = *(const f16x8*)&H0[s0b][(4 + q) * 128 + n * 8];
            const f16x8 a0  = *(const f16x8*)&H1[sp][q * 128 + n * 8];
            const f16x8 a1  = *(const f16x8*)&H1[sp][(4 + q) * 128 + n * 8];

            f32x4 d0, d1, d2, d3;
            {   // 16 independent MFMAs: b1 + Wih1.h0[t-2] + Whh1.h1[t-3]
                f32x4 p0 = MFMA(FR[0], h00, biasv[0]);
                f32x4 p1 = MFMA(FR[1], h01, zero4);
                f32x4 p2 = MFMA(FR[2], a0, zero4);
                f32x4 p3 = MFMA(FR[3], a1, zero4);
                d0 = (p0 + p1) + (p2 + p3);
                p0 = MFMA(FR[4], h00, biasv[1]);
                p1 = MFMA(FR[5], h01, zero4);
                p2 = MFMA(FR[6], a0, zero4);
                p3 = MFMA(FR[7], a1, zero4);
                d1 = (p0 + p1) + (p2 + p3);
                p0 = MFMA(FR[8], h00, biasv[2]);
                p1 = MFMA(FR[9], h01, zero4);
                p2 = MFMA(FR[10], a0, zero4);
                p3 = MFMA(FR[11], a1, zero4);
                d2 = (p0 + p1) + (p2 + p3);
                p0 = MFMA(FR[12], h00, biasv[3]);
                p1 = MFMA(FR[13], h01, zero4);
                p2 = MFMA(FR[14], a0, zero4);
                p3 = MFMA(FR[15], a1, zero4);
                d3 = (p0 + p1) + (p2 + p3);
            }
            const int s2 = t - 2;
            if (s2 >= 0 && s2 < TT) {
                float hv[4];
                #pragma unroll
                for (int r2 = 0; r2 < 4; ++r2) {
                    float i_ = fast_sig(d0[r2]), f_ = fast_sig(d1[r2]);
                    float g_ = fast_tanh(d2[r2]), o_ = fast_sig(d3[r2]);
                    cst[r2] = f_ * cst[r2] + i_ * g_;
                    hv[r2] = o_ * fast_tanh(cst[r2]);
                }
                f16x4 hh = {(_Float16)hv[0], (_Float16)hv[1],
                            (_Float16)hv[2], (_Float16)hv[3]};
                *(f16x4*)&H1[sc][(2 * w + (q >> 1)) * 128 + n * 8 + (q & 1) * 4] = hh;
            }
            if (w == 0) {   // FC2 @ s4 = t-4
                const f16x8 r0 = *(const f16x8*)&Rb[sc][q * 128 + n * 8];
                const f16x8 r1 = *(const f16x8*)&Rb[sc][(4 + q) * 128 + n * 8];
                f32x4 o0 = MFMA(FR[16], r0, biasF);
                f32x4 o1 = MFMA(FR[17], r1, zero4);
                f32x4 ov = o0 + o1;
                const int s4 = t - 4;
                if (s4 >= 0 && s4 < TT) {
                    float* po = outbase + (size_t)n * TT * OO + (size_t)s4 * OO;
                    if (q == 0) {
                        *(f32x2*)(po + 0) = f32x2{ov[0], ov[1]};
                        *(f32x2*)(po + 2) = f32x2{ov[2], ov[3]};
                    } else if (q == 1) {
                        *(f32x2*)(po + 4) = f32x2{ov[0], ov[1]};
                    }
                }
            }
            if (wid == 7 && lane < MB) {   // publish x[t+1] tile
                *(f16x4*)&XT[sp][lane * 8] =
                    f16x4{(_Float16)u0[0], (_Float16)u0[1],
                          (_Float16)u1[0], (_Float16)u1[1]};
                *(f16x2*)&XT[sp][lane * 8 + 4] =
                    f16x2{(_Float16)u2[0], (_Float16)u2[1]};
            }
        }
        LGKM_BARRIER();   // LDS-only drain; global ops stay in flight
    }
}

extern "C" void kernel_launch(void* const* d_in, const int* in_sizes, int n_in,
                              void* d_out, int out_size, void* d_ws, size_t ws_size,
                              hipStream_t stream) {
    const float* xp   = (const float*)d_in[0];
    const float* Wih0 = (const float*)d_in[1];
    const float* Whh0 = (const float*)d_in[2];
    const float* b0   = (const float*)d_in[3];
    const float* Wih1 = (const float*)d_in[4];
    const float* Whh1 = (const float*)d_in[5];
    const float* b1   = (const float*)d_in[6];
    const float* W1   = (const float*)d_in[7];
    const float* bf1  = (const float*)d_in[8];
    const float* W2   = (const float*)d_in[9];
    const float* bf2  = (const float*)d_in[10];
    float* outp = (float*)d_out;

    lstm_mfma_kernel<<<dim3(256 / MB), dim3(NTHR), 0, stream>>>(
        xp, Wih0, Whh0, b0, Wih1, Whh1, b1, W1, bf1, W2, bf2, outp);
}

// Round 20
// 2132.084 us; speedup vs baseline: 1.0724x; 1.0383x over previous
//
#include <hip/hip_runtime.h>

#define TT 2048
#define HH 64
#define II 6
#define OO 6
#define MB 16      // batch rows per group
#define NG 16      // groups; grid = 2*NG blocks (P: 0..15, C: 16..31)
#define RING 256   // h0 ring depth (steps), power of 2
#define NTHR 512

typedef float    f32x4 __attribute__((ext_vector_type(4)));
typedef float    f32x2 __attribute__((ext_vector_type(2)));
typedef _Float16 f16x8 __attribute__((ext_vector_type(8)));
typedef _Float16 f16x4 __attribute__((ext_vector_type(4)));
typedef _Float16 f16x2 __attribute__((ext_vector_type(2)));

__device__ __forceinline__ float fast_sig(float v) {
    return __builtin_amdgcn_rcpf(1.0f + __expf(-v));
}
__device__ __forceinline__ float fast_tanh(float v) {
    return 1.0f - 2.0f * __builtin_amdgcn_rcpf(__expf(2.0f * v) + 1.0f);
}

#define MFMA(a, b, c) __builtin_amdgcn_mfma_f32_16x16x32_f16((a), (b), (c), 0, 0, 0)
#define LGKM_BARRIER() asm volatile("s_waitcnt lgkmcnt(0)\ns_barrier" ::: "memory")

__global__
__attribute__((amdgpu_flat_work_group_size(NTHR, NTHR)))
__attribute__((amdgpu_waves_per_eu(2, 2)))
void lstm_pipe_kernel(const float* __restrict__ x,
                      const float* __restrict__ Wih0, const float* __restrict__ Whh0,
                      const float* __restrict__ b0,
                      const float* __restrict__ Wih1, const float* __restrict__ Whh1,
                      const float* __restrict__ b1,
                      const float* __restrict__ W1, const float* __restrict__ bf1,
                      const float* __restrict__ W2, const float* __restrict__ bf2,
                      float* __restrict__ out, void* __restrict__ ws)
{
    const int bid  = blockIdx.x;
    const bool isP = bid < NG;           // P: layer0 producer; C: layer1+FC consumer
    const int g    = isP ? bid : bid - NG;
    const int row0 = g * MB;
    const int tid  = threadIdx.x;
    const int wid  = tid >> 6;
    const int lane = tid & 63;
    const int n    = lane & 15;          // B-col = batch; A-row = per-tile row
    const int q    = lane >> 4;          // k-group; D rows = units 4q+r (within tile)

    int* p0p = (int*)ws + (size_t)g * 64;          // published h0 steps (count)
    int* c0p = (int*)ws + (size_t)(NG + g) * 64;   // consumer progress
    _Float16* ring = (_Float16*)((char*)ws + 65536) + (size_t)g * (RING * 1024);

    // -------- LDS (frag layout everywhere: [kchunk(8)][batch(16)][8 f16]) --------
    __shared__ __attribute__((aligned(16))) _Float16 H0 [4][1024];   // P: h0 slots t&3
    __shared__ __attribute__((aligned(16))) _Float16 XT [2][128];    // P: x tile
    __shared__ __attribute__((aligned(16))) float    XG0[2][4][4][64][4]; // P: xg0
    __shared__ __attribute__((aligned(16))) _Float16 H0G[4][1024];   // C: staged h0
    __shared__ __attribute__((aligned(16))) _Float16 H1 [2][1024];   // C: h1
    __shared__ __attribute__((aligned(16))) _Float16 Rb [2][1024];   // C: relu(FC1)
    __shared__ __attribute__((aligned(16))) float    XG1[2][4][4][64][4]; // C: xg1

    for (int i = tid; i < 4 * 1024; i += NTHR) { H0[0][i] = (_Float16)0.f;
                                                 H0G[0][i] = (_Float16)0.f; }
    for (int i = tid; i < 2 * 1024; i += NTHR) { H1[0][i] = (_Float16)0.f;
                                                 Rb[0][i]  = (_Float16)0.f; }
    if (tid < 2 * 128) XT[0][tid] = (_Float16)0.f;

    // weight A-frag builder: elem i <-> k = kbase + 8q + i (cancels vs B-frag reads)
    auto mk = [&](const float* W, int r, int ld, int kbase, int kmax, bool rok) {
        f16x8 f;
        #pragma unroll
        for (int i = 0; i < 8; ++i) {
            int kk = kbase + 8 * q + i;
            f[i] = (rok && kk < kmax) ? (_Float16)W[r * ld + kk] : (_Float16)0.f;
        }
        return f;
    };
    const f32x4 zero4 = {0.f, 0.f, 0.f, 0.f};
    f16x8 zero8;
    #pragma unroll
    for (int i = 0; i < 8; ++i) zero8[i] = (_Float16)0.f;

    f16x8 FR[16];
    f32x4 B[8];
    #pragma unroll
    for (int i = 0; i < 16; ++i) FR[i] = zero8;
    #pragma unroll
    for (int i = 0; i < 8; ++i) B[i] = zero4;

    if (isP) {
        if (wid < 4) {                 // W0: Whh0, unit-tile wid, 4 gates x 2 chunks
            #pragma unroll
            for (int gg = 0; gg < 4; ++gg) {
                const int r0 = gg * HH + 16 * wid + n;
                FR[2 * gg + 0] = mk(Whh0, r0, HH, 0,  HH, true);
                FR[2 * gg + 1] = mk(Whh0, r0, HH, 32, HH, true);
            }
        } else if (wid < 6) {          // XA: Wih0 (1 chunk), tiles 2j,2j+1; b0 C-init
            const int j = wid - 4;
            #pragma unroll
            for (int ti = 0; ti < 2; ++ti)
                #pragma unroll
                for (int gg = 0; gg < 4; ++gg) {
                    const int tau = 2 * j + ti;
                    FR[ti * 4 + gg] = mk(Wih0, gg * HH + 16 * tau + n, II, 0, II, true);
                    const int u0 = gg * HH + 16 * tau + 4 * q;
                    B[ti * 4 + gg] = f32x4{b0[u0], b0[u0+1], b0[u0+2], b0[u0+3]};
                }
        }
    } else {
        if (wid < 4) {                 // W1: Whh1
            #pragma unroll
            for (int gg = 0; gg < 4; ++gg) {
                const int r0 = gg * HH + 16 * wid + n;
                FR[2 * gg + 0] = mk(Whh1, r0, HH, 0,  HH, true);
                FR[2 * gg + 1] = mk(Whh1, r0, HH, 32, HH, true);
            }
        } else if (wid < 6) {          // WX: Wih1 (2 chunks), tiles 2j,2j+1; b1 C-init
            const int j = wid - 4;
            #pragma unroll
            for (int ti = 0; ti < 2; ++ti)
                #pragma unroll
                for (int gg = 0; gg < 4; ++gg) {
                    const int tau = 2 * j + ti;
                    const int r0 = gg * HH + 16 * tau + n;
                    FR[(ti * 4 + gg) * 2 + 0] = mk(Wih1, r0, HH, 0,  HH, true);
                    FR[(ti * 4 + gg) * 2 + 1] = mk(Wih1, r0, HH, 32, HH, true);
                    const int u0 = gg * HH + 16 * tau + 4 * q;
                    B[ti * 4 + gg] = f32x4{b1[u0], b1[u0+1], b1[u0+2], b1[u0+3]};
                }
        } else if (wid == 7) {         // FC: FR[0..7]=W1 tiles, FR[8..9]=W2; B[0..3]=bf1, B[4]=bf2
            #pragma unroll
            for (int tau = 0; tau < 4; ++tau) {
                FR[2 * tau + 0] = mk(W1, 16 * tau + n, HH, 0,  HH, true);
                FR[2 * tau + 1] = mk(W1, 16 * tau + n, HH, 32, HH, true);
                const int u0 = 16 * tau + 4 * q;
                B[tau] = f32x4{bf1[u0], bf1[u0+1], bf1[u0+2], bf1[u0+3]};
            }
            FR[8] = mk(W2, n, HH, 0,  HH, n < OO);
            FR[9] = mk(W2, n, HH, 32, HH, n < OO);
            #pragma unroll
            for (int r2 = 0; r2 < 4; ++r2) {
                const int u = 4 * q + r2;
                B[4][r2] = (u < OO) ? bf2[u] : 0.f;
            }
        }
    }

    // P prologue: XA computes xg0[0] from directly-loaded x[0]; stager stages x[1]
    const float* xs = nullptr;
    if (isP && wid == 6 && lane < MB) {
        const float* p = x + (size_t)(row0 + lane) * TT * II;
        unsigned long long pp = (unsigned long long)p;
        asm volatile("" : "+v"(pp));
        xs = (const float*)pp;
        f32x2 u0 = *(const f32x2*)(xs + II + 0);   // x[1]
        f32x2 u1 = *(const f32x2*)(xs + II + 2);
        f32x2 u2 = *(const f32x2*)(xs + II + 4);
        *(f16x4*)&XT[1][lane * 8] = f16x4{(_Float16)u0[0], (_Float16)u0[1],
                                          (_Float16)u1[0], (_Float16)u1[1]};
        *(f16x2*)&XT[1][lane * 8 + 4] = f16x2{(_Float16)u2[0], (_Float16)u2[1]};
    }
    if (isP && (wid == 4 || wid == 5)) {
        const int j = wid - 4;
        f16x8 xb = zero8;
        if (q == 0) {
            const float* xp = x + (size_t)(row0 + n) * TT * II;
            f32x2 a = *(const f32x2*)(xp + 0);
            f32x2 b = *(const f32x2*)(xp + 2);
            f32x2 c = *(const f32x2*)(xp + 4);
            xb = f16x8{(_Float16)a[0], (_Float16)a[1], (_Float16)b[0], (_Float16)b[1],
                       (_Float16)c[0], (_Float16)c[1], (_Float16)0.f, (_Float16)0.f};
        }
        #pragma unroll
        for (int ti = 0; ti < 2; ++ti)
            #pragma unroll
            for (int gg = 0; gg < 4; ++gg) {
                f32x4 acc = MFMA(FR[ti * 4 + gg], xb, B[ti * 4 + gg]);
                *(f32x4*)&XG0[0][2 * j + ti][gg][lane][0] = acc;
            }
    }

    auto cellact = [&](const f32x4& d0, const f32x4& d1, const f32x4& d2,
                       const f32x4& d3, f32x4& cs) {
        f16x4 hh;
        #pragma unroll
        for (int r2 = 0; r2 < 4; ++r2) {
            float i_ = fast_sig(d0[r2]), f_ = fast_sig(d1[r2]);
            float g_ = fast_tanh(d2[r2]), o_ = fast_sig(d3[r2]);
            cs[r2] = f_ * cs[r2] + i_ * g_;
            hh[r2] = (_Float16)(o_ * fast_tanh(cs[r2]));
        }
        return hh;
    };

    f32x4 cst = zero4;
    __syncthreads();

    const int EMAX = isP ? TT : TT + 4;
    for (int e = 0; e <= EMAX; ++e) {
        if (isP) {
            if (wid < 4) {                    // ---- W0: layer0 step e
                const f16x8 a0 = *(const f16x8*)&H0[(e + 3) & 3][q * 128 + n * 8];
                const f16x8 a1 = *(const f16x8*)&H0[(e + 3) & 3][512 + q * 128 + n * 8];
                f32x4 d0, d1, d2, d3;
                #pragma unroll
                for (int gg = 0; gg < 4; ++gg) {
                    f32x4 xg = *(const f32x4*)&XG0[e & 1][wid][gg][lane][0];
                    f32x4 pA = MFMA(FR[2 * gg + 0], a0, xg);
                    f32x4 pB = MFMA(FR[2 * gg + 1], a1, zero4);
                    f32x4 d = pA + pB;
                    if (gg == 0) d0 = d; else if (gg == 1) d1 = d;
                    else if (gg == 2) d2 = d; else d3 = d;
                }
                if (e < TT) {
                    f16x4 hh = cellact(d0, d1, d2, d3, cst);
                    *(f16x4*)&H0[e & 3][(2 * wid + (q >> 1)) * 128 + n * 8 + (q & 1) * 4] = hh;
                }
            } else if (wid < 6) {             // ---- XA: xg0[e+1]
                if (e + 1 < TT) {
                    const int j = wid - 4;
                    f16x8 xb = zero8;
                    if (q == 0) xb = *(const f16x8*)&XT[(e + 1) & 1][n * 8];
                    #pragma unroll
                    for (int ti = 0; ti < 2; ++ti)
                        #pragma unroll
                        for (int gg = 0; gg < 4; ++gg) {
                            f32x4 acc = MFMA(FR[ti * 4 + gg], xb, B[ti * 4 + gg]);
                            *(f32x4*)&XG0[(e + 1) & 1][2 * j + ti][gg][lane][0] = acc;
                        }
                }
            } else if (wid == 6) {            // ---- stager: x[e+2]
                if (lane < MB && e + 2 < TT) {
                    const float* xp2 = xs + (size_t)(e + 2) * II;
                    f32x2 u0 = *(const f32x2*)(xp2 + 0);
                    f32x2 u1 = *(const f32x2*)(xp2 + 2);
                    f32x2 u2 = *(const f32x2*)(xp2 + 4);
                    *(f16x4*)&XT[e & 1][lane * 8] =
                        f16x4{(_Float16)u0[0], (_Float16)u0[1],
                              (_Float16)u1[0], (_Float16)u1[1]};
                    *(f16x2*)&XT[e & 1][lane * 8 + 4] =
                        f16x2{(_Float16)u2[0], (_Float16)u2[1]};
                }
            } else {                          // ---- publisher: every 2 steps
                if ((e & 1) == 0 && e >= 2) {
                    #pragma unroll
                    for (int d = 2; d >= 1; --d) {
                        const int m = e - d;
                        if (m >= 0 && m < TT) {
                            f16x8 v0 = *(const f16x8*)&H0[m & 3][lane * 16];
                            f16x8 v1 = *(const f16x8*)&H0[m & 3][lane * 16 + 8];
                            _Float16* dst = ring + (size_t)(m & (RING - 1)) * 1024 + lane * 16;
                            *(f16x8*)dst = v0;
                            *(f16x8*)(dst + 8) = v1;
                        }
                    }
                    asm volatile("s_waitcnt vmcnt(0)" ::: "memory");
                    __threadfence();
                    if (lane == 0)
                        __hip_atomic_store(p0p, e, __ATOMIC_RELEASE,
                                           __HIP_MEMORY_SCOPE_AGENT);
                    if (lane == 0 && e >= RING - 64 && (e & 63) == 0) {
                        while (__hip_atomic_load(c0p, __ATOMIC_RELAXED,
                                                 __HIP_MEMORY_SCOPE_AGENT)
                               < e - (RING - 64))
                            __builtin_amdgcn_s_sleep(8);
                    }
                }
            }
        } else {
            if (wid < 4) {                    // ---- W1: layer1 step u = e-3
                const int u = e - 3;
                const f16x8 a0 = *(const f16x8*)&H1[e & 1][q * 128 + n * 8];
                const f16x8 a1 = *(const f16x8*)&H1[e & 1][512 + q * 128 + n * 8];
                f32x4 d0, d1, d2, d3;
                #pragma unroll
                for (int gg = 0; gg < 4; ++gg) {
                    f32x4 xg = *(const f32x4*)&XG1[(e + 1) & 1][wid][gg][lane][0];
                    f32x4 pA = MFMA(FR[2 * gg + 0], a0, xg);
                    f32x4 pB = MFMA(FR[2 * gg + 1], a1, zero4);
                    f32x4 d = pA + pB;
                    if (gg == 0) d0 = d; else if (gg == 1) d1 = d;
                    else if (gg == 2) d2 = d; else d3 = d;
                }
                if (u >= 0 && u < TT) {
                    f16x4 hh = cellact(d0, d1, d2, d3, cst);
                    *(f16x4*)&H1[(e + 1) & 1][(2 * wid + (q >> 1)) * 128 + n * 8 + (q & 1) * 4] = hh;
                }
            } else if (wid < 6) {             // ---- WX: xg1[m2], m2 = e-2
                const int m2 = e - 2;
                if (m2 >= 0 && m2 < TT) {
                    const int j = wid - 4;
                    const f16x8 h0a = *(const f16x8*)&H0G[m2 & 3][q * 128 + n * 8];
                    const f16x8 h0b = *(const f16x8*)&H0G[m2 & 3][512 + q * 128 + n * 8];
                    #pragma unroll
                    for (int ti = 0; ti < 2; ++ti)
                        #pragma unroll
                        for (int gg = 0; gg < 4; ++gg) {
                            f32x4 acc = MFMA(FR[(ti * 4 + gg) * 2 + 0], h0a, B[ti * 4 + gg]);
                            f32x4 ac2 = MFMA(FR[(ti * 4 + gg) * 2 + 1], h0b, zero4);
                            *(f32x4*)&XG1[m2 & 1][2 * j + ti][gg][lane][0] = acc + ac2;
                        }
                }
            } else if (wid == 6) {            // ---- ring reader: every 2 epochs
                if ((e & 1) == 0) {
                    const int mHi = (e < TT) ? e : TT - 1;
                    if (mHi >= 0 && e - 1 < TT) {
                        int pv = 0;
                        if (lane == 0) {
                            pv = __hip_atomic_load(p0p, __ATOMIC_RELAXED,
                                                   __HIP_MEMORY_SCOPE_AGENT);
                            while (pv < mHi + 1) {
                                __builtin_amdgcn_s_sleep(8);
                                pv = __hip_atomic_load(p0p, __ATOMIC_RELAXED,
                                                       __HIP_MEMORY_SCOPE_AGENT);
                            }
                        }
                        __threadfence();
                        #pragma unroll
                        for (int d = 1; d >= 0; --d) {
                            const int m = e - d;
                            if (m >= 0 && m < TT) {
                                const _Float16* src =
                                    ring + (size_t)(m & (RING - 1)) * 1024 + lane * 16;
                                f16x8 v0 = *(const f16x8*)src;
                                f16x8 v1 = *(const f16x8*)(src + 8);
                                *(f16x8*)&H0G[m & 3][lane * 16] = v0;
                                *(f16x8*)&H0G[m & 3][lane * 16 + 8] = v1;
                            }
                        }
                    }
                    if (lane == 0 && (e & 63) == 0)
                        __hip_atomic_store(c0p, e, __ATOMIC_RELAXED,
                                           __HIP_MEMORY_SCOPE_AGENT);
                }
            } else {                          // ---- FC: FC1 @ v=e-4, FC2 @ v2=e-5
                const int v = e - 4, v2 = e - 5;
                const f16x8 b0f = *(const f16x8*)&H1[e & 1][q * 128 + n * 8];
                const f16x8 b1f = *(const f16x8*)&H1[e & 1][512 + q * 128 + n * 8];
                #pragma unroll
                for (int tau = 0; tau < 4; ++tau) {
                    f32x4 acc = MFMA(FR[2 * tau + 0], b0f, B[tau]);
                    f32x4 ac2 = MFMA(FR[2 * tau + 1], b1f, zero4);
                    f32x4 fv = acc + ac2;
                    if (v >= 0 && v < TT) {
                        f16x4 rv = {(_Float16)fmaxf(fv[0], 0.f), (_Float16)fmaxf(fv[1], 0.f),
                                    (_Float16)fmaxf(fv[2], 0.f), (_Float16)fmaxf(fv[3], 0.f)};
                        *(f16x4*)&Rb[e & 1][(2 * tau + (q >> 1)) * 128 + n * 8 + (q & 1) * 4] = rv;
                    }
                }
                const f16x8 r0 = *(const f16x8*)&Rb[(e + 1) & 1][q * 128 + n * 8];
                const f16x8 r1 = *(const f16x8*)&Rb[(e + 1) & 1][512 + q * 128 + n * 8];
                f32x4 o0 = MFMA(FR[8], r0, B[4]);
                f32x4 o1 = MFMA(FR[9], r1, zero4);
                f32x4 ov = o0 + o1;
                if (v2 >= 0 && v2 < TT) {
                    float* po = out + (size_t)(row0 + n) * TT * OO + (size_t)v2 * OO;
                    if (q == 0) {
                        *(f32x2*)(po + 0) = f32x2{ov[0], ov[1]};
                        *(f32x2*)(po + 2) = f32x2{ov[2], ov[3]};
                    } else if (q == 1) {
                        *(f32x2*)(po + 4) = f32x2{ov[0], ov[1]};
                    }
                }
            }
        }
        LGKM_BARRIER();   // block-local; global ops stay in flight
    }
}

extern "C" void kernel_launch(void* const* d_in, const int* in_sizes, int n_in,
                              void* d_out, int out_size, void* d_ws, size_t ws_size,
                              hipStream_t stream) {
    const float* xp   = (const float*)d_in[0];
    const float* Wih0 = (const float*)d_in[1];
    const float* Whh0 = (const float*)d_in[2];
    const float* b0   = (const float*)d_in[3];
    const float* Wih1 = (const float*)d_in[4];
    const float* Whh1 = (const float*)d_in[5];
    const float* b1   = (const float*)d_in[6];
    const float* W1   = (const float*)d_in[7];
    const float* bf1  = (const float*)d_in[8];
    const float* W2   = (const float*)d_in[9];
    const float* bf2  = (const float*)d_in[10];
    float* outp = (float*)d_out;

    // zero the flag region (p0/c0 counters) every call — deterministic replays
    hipMemsetAsync(d_ws, 0, 65536, stream);
    lstm_pipe_kernel<<<dim3(2 * NG), dim3(NTHR), 0, stream>>>(
        xp, Wih0, Whh0, b0, Wih1, Whh1, b1, W1, bf1, W2, bf2, outp, d_ws);
}